// Round 1
// baseline (1855.577 us; speedup 1.0000x reference)
//
#include <hip/hip_runtime.h>

// PhotonicNetworkGPU: B=32, S=256, W=64, M=64, 4 fused integration steps.
// One block per (b, w, m-half): field tile 256(s) x 32(m) complex resident in
// LDS (interleaved re/im -> 64 KiB exactly, 2 blocks/CU).
// Per step: dense fp32 GEMM coupled = conn @ tile with 8x8 register tiling,
// then pointwise gain/bias/saturation/phase/decay on thread-owned elements.

#define NB 32
#define NS 256
#define NW 64
#define NM 64
#define PLANE (NB * NS * NW * NM)

__global__ __launch_bounds__(256, 2)
void photonic_fused(const float* __restrict__ fr, const float* __restrict__ fi,
                    const float* __restrict__ conn, const float* __restrict__ gain,
                    const float* __restrict__ bias, const float* __restrict__ ww,
                    const float* __restrict__ dshape, float* __restrict__ out)
{
    // fld[s][slot], slot = float4; floats within row: c = 2*m_local + comp
    __shared__ float4 fld[NS * 16];   // 64 KiB

    const int t   = threadIdx.x;
    const int bid = blockIdx.x;
    const int b   = bid >> 7;          // 0..31
    const int w   = (bid >> 1) & 63;   // 0..63
    const int h   = bid & 1;           // which half of m (0..1)

    const int tr = t >> 3;             // 0..31 : owns rows tr*8 .. tr*8+7
    const int tc = t & 7;              // 0..7  : owns float-cols tc*8 .. tc*8+7

    // ---------- stage tile into LDS (interleave re/im per m) ----------
    {
        const int q  = t & 7;          // m-quad: m_local = 4q..4q+3
        const int r0 = t >> 3;         // 0..31
        #pragma unroll
        for (int pass = 0; pass < 8; ++pass) {
            const int s = pass * 32 + r0;
            const int gbase = ((b * NS + s) * NW + w) * NM + h * 32 + q * 4;
            const float4 re = *reinterpret_cast<const float4*>(fr + gbase);
            const float4 im = *reinterpret_cast<const float4*>(fi + gbase);
            fld[s * 16 + q * 2 + 0] = make_float4(re.x, im.x, re.y, im.y);
            fld[s * 16 + q * 2 + 1] = make_float4(re.z, im.z, re.w, im.w);
        }
    }

    // ---------- per-thread constants ----------
    float g8[8], bb8[8], dw8[8];
    #pragma unroll
    for (int i = 0; i < 8; ++i) {
        const int si = tr * 8 + i;
        g8[i]  = gain[si];
        bb8[i] = bias[si];
        dw8[i] = 0.95f * ww[si * NW + w];   // (1 - CAVITY_LOSS) * wavelength_weights
    }
    const float th  = 0.1f * dshape[w];     // DISPERSION_STRENGTH * dispersion_shape
    const float pr  = cosf(th);
    const float pim = sinf(th);

    const float4* __restrict__ cv = reinterpret_cast<const float4*>(conn); // 64 f4/row

    for (int step = 0; step < 4; ++step) {
        __syncthreads();   // tile (re)written -> visible to everyone

        float acc[8][8];
        #pragma unroll
        for (int i = 0; i < 8; ++i)
            #pragma unroll
            for (int u = 0; u < 8; ++u) acc[i][u] = 0.0f;

        // ---- coupled = conn @ tile (k over source rows) ----
        for (int k4 = 0; k4 < 64; ++k4) {
            float4 a4[8];
            #pragma unroll
            for (int i = 0; i < 8; ++i) a4[i] = cv[(tr * 8 + i) * 64 + k4];
            #pragma unroll
            for (int kk = 0; kk < 4; ++kk) {
                const int k = k4 * 4 + kk;
                const float4 b0 = fld[k * 16 + tc * 2 + 0];
                const float4 b1 = fld[k * 16 + tc * 2 + 1];
                #pragma unroll
                for (int i = 0; i < 8; ++i) {
                    const float a = reinterpret_cast<const float*>(&a4[i])[kk];
                    acc[i][0] = fmaf(a, b0.x, acc[i][0]);
                    acc[i][1] = fmaf(a, b0.y, acc[i][1]);
                    acc[i][2] = fmaf(a, b0.z, acc[i][2]);
                    acc[i][3] = fmaf(a, b0.w, acc[i][3]);
                    acc[i][4] = fmaf(a, b1.x, acc[i][4]);
                    acc[i][5] = fmaf(a, b1.y, acc[i][5]);
                    acc[i][6] = fmaf(a, b1.z, acc[i][6]);
                    acc[i][7] = fmaf(a, b1.w, acc[i][7]);
                }
            }
        }

        __syncthreads();   // every thread done READING fld for this step

        // ---- pointwise update; each thread RMWs only positions it owns ----
        #pragma unroll
        for (int i = 0; i < 8; ++i) {
            const int si = tr * 8 + i;
            const float4 o0 = fld[si * 16 + tc * 2 + 0];
            const float4 o1 = fld[si * 16 + tc * 2 + 1];
            const float oldr[4] = {o0.x, o0.z, o1.x, o1.z};
            const float oldi[4] = {o0.y, o0.w, o1.y, o1.w};
            float rr[4], ii[4];
            #pragma unroll
            for (int u = 0; u < 4; ++u) {
                float re = g8[i] * (oldr[u] + acc[i][2 * u])     + bb8[i];
                float im = g8[i] * (oldi[u] + acc[i][2 * u + 1]);
                const float inten = re * re + im * im;
                const float inv   = 1.0f / (1.0f + 0.5f * inten);   // /SATURATION
                re *= inv; im *= inv;
                rr[u] = (re * pr  - im * pim) * dw8[i];
                ii[u] = (re * pim + im * pr ) * dw8[i];
            }
            if (step < 3) {
                fld[si * 16 + tc * 2 + 0] = make_float4(rr[0], ii[0], rr[1], ii[1]);
                fld[si * 16 + tc * 2 + 1] = make_float4(rr[2], ii[2], rr[3], ii[3]);
            } else {
                const int obase = ((b * NS + si) * NW + w) * NM + h * 32 + tc * 4;
                *reinterpret_cast<float4*>(out + obase)         = make_float4(rr[0], rr[1], rr[2], rr[3]);
                *reinterpret_cast<float4*>(out + PLANE + obase) = make_float4(ii[0], ii[1], ii[2], ii[3]);
            }
        }
    }
}

extern "C" void kernel_launch(void* const* d_in, const int* in_sizes, int n_in,
                              void* d_out, int out_size, void* d_ws, size_t ws_size,
                              hipStream_t stream)
{
    const float* fr = (const float*)d_in[0];  // field_real  (B,S,W,M)
    const float* fi = (const float*)d_in[1];  // field_imag  (B,S,W,M)
    const float* cn = (const float*)d_in[2];  // connectivity (S,S)
    const float* gn = (const float*)d_in[3];  // gain (S)
    const float* bs = (const float*)d_in[4];  // bias (S)
    const float* wwp= (const float*)d_in[5];  // wavelength_weights (S,W)
    const float* ds = (const float*)d_in[6];  // dispersion_shape (W)
    float* out = (float*)d_out;               // (2,B,S,W,M) fp32

    dim3 grid(NB * NW * 2);
    dim3 blk(256);
    hipLaunchKernelGGL(photonic_fused, grid, blk, 0, stream,
                       fr, fi, cn, gn, bs, wwp, ds, out);
}

// Round 2
// 1141.749 us; speedup vs baseline: 1.6252x; 1.6252x over previous
//
#include <hip/hip_runtime.h>

// PhotonicNetworkGPU on MI355X — bf16 MFMA version.
// Per (b, w, m-half) block: field tile (256 s x 32 m x {re,im}) lives in LDS as
// bf16, TRANSPOSED: fldT[col][s], col = comp*32 + m_local, pitch 264 bf16.
// Per step: coupled = conn @ field via mfma_f32_32x32x16_bf16 (wave = 64 rows
// x 64 cols = 2x2 tiles, K=256 in 16 iters). conn is bf16 in d_ws (prep
// kernel), read as A-fragments directly from global (L1/L2 resident).
// fp32 field STATE is kept in registers (C/D-layout ownership is constant
// across steps); only MFMA operands are bf16-rounded.

#define NB 32
#define NS 256
#define NW 64
#define NM 64
#define PLANE (NB * NS * NW * NM)
#define PITCH 264   // 256 + 8 bf16: 528 B col stride -> quad stride 33 (odd) -> conflict-free b128

typedef short bfrag __attribute__((ext_vector_type(8)));
typedef short bfx4  __attribute__((ext_vector_type(4)));
typedef float accv  __attribute__((ext_vector_type(16)));

__device__ __forceinline__ short f2bf(float x) {   // RNE truncate f32 -> bf16
    union { float f; unsigned u; } v; v.f = x;
    unsigned r = (v.u + 0x7fffu + ((v.u >> 16) & 1u)) >> 16;
    return (short)r;
}
__device__ __forceinline__ float bf2f(short s) {
    union { unsigned u; float f; } v; v.u = ((unsigned)(unsigned short)s) << 16;
    return v.f;
}

__global__ __launch_bounds__(256)
void conn_to_bf16(const float* __restrict__ c, short* __restrict__ o) {
    const int i = (blockIdx.x * 256 + threadIdx.x) * 4;   // 64 blocks cover 65536
    const float4 v = *reinterpret_cast<const float4*>(c + i);
    unsigned lo = (unsigned short)f2bf(v.x) | ((unsigned)(unsigned short)f2bf(v.y) << 16);
    unsigned hi = (unsigned short)f2bf(v.z) | ((unsigned)(unsigned short)f2bf(v.w) << 16);
    *reinterpret_cast<uint2*>(o + i) = make_uint2(lo, hi);
}

__global__ __launch_bounds__(256, 2)
void photonic_mfma(const float* __restrict__ fr, const float* __restrict__ fi,
                   const short* __restrict__ cb, const float* __restrict__ gain,
                   const float* __restrict__ bias, const float* __restrict__ ww,
                   const float* __restrict__ dshape, float* __restrict__ out)
{
    __shared__ __align__(16) short fldT[64 * PITCH];   // 33,792 B
    __shared__ float4 cons[NS];                        // (gain, bias, 0.95*ww, -)

    const int t    = threadIdx.x;
    const int bid  = blockIdx.x;
    const int b    = bid >> 7;
    const int w    = (bid >> 1) & 63;
    const int h    = bid & 1;

    const int wv      = t >> 6;
    const int lane    = t & 63;
    const int half    = lane >> 5;
    const int l31     = lane & 31;
    const int rowbase = wv * 64;

    // ---------------- stage field -> LDS (bf16, transposed) ----------------
    {
        const int q  = t & 7;          // m-quad
        const int r0 = t >> 3;         // s mod 32
        #pragma unroll
        for (int pass = 0; pass < 8; ++pass) {
            const int s = pass * 32 + r0;
            const int g = ((b * NS + s) * NW + w) * NM + h * 32 + q * 4;
            const float4 re = *reinterpret_cast<const float4*>(fr + g);
            const float4 im = *reinterpret_cast<const float4*>(fi + g);
            fldT[(q * 4 + 0) * PITCH + s] = f2bf(re.x);
            fldT[(q * 4 + 1) * PITCH + s] = f2bf(re.y);
            fldT[(q * 4 + 2) * PITCH + s] = f2bf(re.z);
            fldT[(q * 4 + 3) * PITCH + s] = f2bf(re.w);
            fldT[(32 + q * 4 + 0) * PITCH + s] = f2bf(im.x);
            fldT[(32 + q * 4 + 1) * PITCH + s] = f2bf(im.y);
            fldT[(32 + q * 4 + 2) * PITCH + s] = f2bf(im.z);
            fldT[(32 + q * 4 + 3) * PITCH + s] = f2bf(im.w);
        }
    }
    if (t < NS) cons[t] = make_float4(gain[t], bias[t], 0.95f * ww[t * NW + w], 0.0f);

    const float th  = 0.1f * dshape[w];
    const float cpr = cosf(th);
    const float cpi = sinf(th);

    __syncthreads();

    // ------------- fp32 register state for the lane's owned elements -------
    // ownership (per C/D layout): s = rowbase + rt*32 + q*8 + 4*half + j, m = l31
    float sr[2][16], si[2][16];
    #pragma unroll
    for (int rt = 0; rt < 2; ++rt)
        #pragma unroll
        for (int q = 0; q < 4; ++q) {
            const int srow = rowbase + rt * 32 + q * 8 + 4 * half;
            const bfx4 r4 = *reinterpret_cast<const bfx4*>(&fldT[l31 * PITCH + srow]);
            const bfx4 i4 = *reinterpret_cast<const bfx4*>(&fldT[(32 + l31) * PITCH + srow]);
            #pragma unroll
            for (int j = 0; j < 4; ++j) {
                sr[rt][q * 4 + j] = bf2f(r4[j]);
                si[rt][q * 4 + j] = bf2f(i4[j]);
            }
        }

    const short* arow0 = cb + (rowbase + l31) * NS + half * 8;        // A rows, rt=0
    const short* arow1 = arow0 + 32 * NS;                             // rt=1
    const short* bcol0 = &fldT[l31 * PITCH + half * 8];               // B cols, re
    const short* bcol1 = &fldT[(32 + l31) * PITCH + half * 8];        // im

    for (int step = 0; step < 4; ++step) {
        if (step > 0) __syncthreads();   // prev epilogue writes -> visible

        accv acc[2][2];
        #pragma unroll
        for (int rt = 0; rt < 2; ++rt)
            #pragma unroll
            for (int ct = 0; ct < 2; ++ct)
                #pragma unroll
                for (int r = 0; r < 16; ++r) acc[rt][ct][r] = 0.0f;

        #pragma unroll
        for (int k0 = 0; k0 < NS; k0 += 16) {
            const bfrag A0 = *reinterpret_cast<const bfrag*>(arow0 + k0);
            const bfrag A1 = *reinterpret_cast<const bfrag*>(arow1 + k0);
            const bfrag B0 = *reinterpret_cast<const bfrag*>(bcol0 + k0);
            const bfrag B1 = *reinterpret_cast<const bfrag*>(bcol1 + k0);
            acc[0][0] = __builtin_amdgcn_mfma_f32_32x32x16_bf16(A0, B0, acc[0][0], 0, 0, 0);
            acc[0][1] = __builtin_amdgcn_mfma_f32_32x32x16_bf16(A0, B1, acc[0][1], 0, 0, 0);
            acc[1][0] = __builtin_amdgcn_mfma_f32_32x32x16_bf16(A1, B0, acc[1][0], 0, 0, 0);
            acc[1][1] = __builtin_amdgcn_mfma_f32_32x32x16_bf16(A1, B1, acc[1][1], 0, 0, 0);
        }

        __syncthreads();   // everyone done reading fldT

        if (step < 3) {
            #pragma unroll
            for (int rt = 0; rt < 2; ++rt)
                #pragma unroll
                for (int q = 0; q < 4; ++q) {
                    const int srow = rowbase + rt * 32 + q * 8 + 4 * half;
                    unsigned short pr_[4], pi_[4];
                    #pragma unroll
                    for (int j = 0; j < 4; ++j) {
                        const int r = q * 4 + j;
                        const float4 cc = cons[srow + j];
                        float re = cc.x * (sr[rt][r] + acc[rt][0][r]) + cc.y;
                        float im = cc.x * (si[rt][r] + acc[rt][1][r]);
                        const float inv = 1.0f / (1.0f + 0.5f * (re * re + im * im));
                        re *= inv; im *= inv;
                        const float nr = (re * cpr - im * cpi) * cc.z;
                        const float ni = (re * cpi + im * cpr) * cc.z;
                        sr[rt][r] = nr; si[rt][r] = ni;
                        pr_[j] = (unsigned short)f2bf(nr);
                        pi_[j] = (unsigned short)f2bf(ni);
                    }
                    const uint2 pre = make_uint2(pr_[0] | ((unsigned)pr_[1] << 16),
                                                 pr_[2] | ((unsigned)pr_[3] << 16));
                    const uint2 pim = make_uint2(pi_[0] | ((unsigned)pi_[1] << 16),
                                                 pi_[2] | ((unsigned)pi_[3] << 16));
                    *reinterpret_cast<uint2*>(&fldT[l31 * PITCH + srow])        = pre;
                    *reinterpret_cast<uint2*>(&fldT[(32 + l31) * PITCH + srow]) = pim;
                }
        } else {
            #pragma unroll
            for (int rt = 0; rt < 2; ++rt)
                #pragma unroll
                for (int q = 0; q < 4; ++q) {
                    const int srow = rowbase + rt * 32 + q * 8 + 4 * half;
                    #pragma unroll
                    for (int j = 0; j < 4; ++j) {
                        const int r = q * 4 + j;
                        const float4 cc = cons[srow + j];
                        float re = cc.x * (sr[rt][r] + acc[rt][0][r]) + cc.y;
                        float im = cc.x * (si[rt][r] + acc[rt][1][r]);
                        const float inv = 1.0f / (1.0f + 0.5f * (re * re + im * im));
                        re *= inv; im *= inv;
                        const float nr = (re * cpr - im * cpi) * cc.z;
                        const float ni = (re * cpi + im * cpr) * cc.z;
                        const int idx = ((b * NS + srow + j) * NW + w) * NM + h * 32 + l31;
                        out[idx]         = nr;   // coalesced: l31 is the fast dim
                        out[PLANE + idx] = ni;
                    }
                }
        }
    }
}

extern "C" void kernel_launch(void* const* d_in, const int* in_sizes, int n_in,
                              void* d_out, int out_size, void* d_ws, size_t ws_size,
                              hipStream_t stream)
{
    const float* fr  = (const float*)d_in[0];
    const float* fi  = (const float*)d_in[1];
    const float* cn  = (const float*)d_in[2];
    const float* gn  = (const float*)d_in[3];
    const float* bs  = (const float*)d_in[4];
    const float* wwp = (const float*)d_in[5];
    const float* ds  = (const float*)d_in[6];
    float* out = (float*)d_out;
    short* cb  = (short*)d_ws;   // 65536 bf16 = 128 KiB

    hipLaunchKernelGGL(conn_to_bf16, dim3(64), dim3(256), 0, stream, cn, cb);
    hipLaunchKernelGGL(photonic_mfma, dim3(NB * NW * 2), dim3(256), 0, stream,
                       fr, fi, cb, gn, bs, wwp, ds, out);
}